// Round 1
// baseline (310.185 us; speedup 1.0000x reference)
//
#include <hip/hip_runtime.h>
#include <math.h>

#define NN 4096
#define DD 512
#define INV_TAU 5.0f
#define EPSV 1e-15f

typedef unsigned short u16;
typedef __attribute__((ext_vector_type(8))) short short8;
typedef __attribute__((ext_vector_type(4))) float f32x4;

__device__ __forceinline__ void gld16(const void* g, void* l) {
  __builtin_amdgcn_global_load_lds(
      (const __attribute__((address_space(1))) unsigned int*)g,
      (__attribute__((address_space(3))) unsigned int*)l, 16, 0, 0);
}

// counted-vmcnt barriers: keep the newest 4 prefetch loads in flight across
// the barrier (T3/T4). lgkmcnt(0) is free here (all ds_reads already consumed
// by MFMAs) and guarantees no read-in-flight when the next buffer write lands.
__device__ __forceinline__ void bar_vm4() {
  asm volatile("s_waitcnt vmcnt(4) lgkmcnt(0)\n\ts_barrier" ::: "memory");
}
__device__ __forceinline__ void bar_vm0() {
  asm volatile("s_waitcnt vmcnt(0) lgkmcnt(0)\n\ts_barrier" ::: "memory");
}

__device__ __forceinline__ float bf2f(u16 u) {
  return __uint_as_float(((unsigned)u) << 16);
}
__device__ __forceinline__ u16 f2bf(float x) {  // RNE
  unsigned u = __float_as_uint(x);
  u += 0x7fff + ((u >> 16) & 1);
  return (u16)(u >> 16);
}

__device__ __forceinline__ float wave_sum(float v) {
#pragma unroll
  for (int o = 32; o > 0; o >>= 1) v += __shfl_down(v, o, 64);
  return v;
}

// ---------------- fp32 -> bf16 convert, two sources -> contiguous dst --------
__global__ __launch_bounds__(256) void tobf16_2(const float* __restrict__ a,
                                                const float* __restrict__ b,
                                                u16* __restrict__ d,
                                                int n4each) {
  const int i = blockIdx.x * 256 + threadIdx.x;
  const float* s =
      (i < n4each) ? a + (size_t)i * 4 : b + (size_t)(i - n4each) * 4;
  float4 v = *(const float4*)s;
  unsigned long long pk = (unsigned long long)f2bf(v.x) |
                          ((unsigned long long)f2bf(v.y) << 16) |
                          ((unsigned long long)f2bf(v.z) << 32) |
                          ((unsigned long long)f2bf(v.w) << 48);
  *(unsigned long long*)&d[(size_t)i * 4] = pk;
}

// ------------- MFMA NT GEMM, depth-3 counted-vmcnt pipeline ------------------
// out = act(A@Bw^T + bias). A:[2,4096,512] bf16, Bw:[512,512] bf16.
// tile 128x128, 4 waves. LDS: 3 bufs x (A panel + B panel) x 8KiB = 48 KiB.
// Bank swizzle: within each 2-row (128B) group, the 16B chunk at linear pos c
// holds logical chunk c ^ (pair&7) (XOR involution; applied on global source
// at staging + on ds_read index — rule #21: both-sides-or-neither).
template <int ACT>
__global__ __launch_bounds__(256) void gemm_mfma(
    const u16* __restrict__ A, const u16* __restrict__ Bw,
    const float* __restrict__ bias, const float* __restrict__ alpha_p,
    u16* __restrict__ out) {
  __shared__ __align__(16) u16 sh[3 * 2 * 128 * 32];  // 48 KiB
  const int tid = threadIdx.x, w = tid >> 6, lane = tid & 63;
  const int quad = lane >> 4, m16 = lane & 15;
  const int wi = w >> 1, wj = w & 1;
  const int i0 = blockIdx.y * 128, j0 = blockIdx.x * 128;
  const u16* Ab = A + (size_t)blockIdx.z * ((size_t)NN * DD);
  u16* ob = out + (size_t)blockIdx.z * ((size_t)NN * DD);
  // swizzled per-lane ds_read offset within a 16-row x 32-col group (u16 units)
  const int roff =
      (m16 >> 1) * 64 + (((((m16 & 1) << 2) | quad) ^ (m16 >> 1)) * 8);
  // staging lane constants: lane l writes linear chunk (l&7) of row-pair
  // (l>>3); it must fetch logical chunk (l&7)^(l>>3) of that pair.
  const int st = (lane & 7) ^ (lane >> 3);
  const int srow = 2 * (lane >> 3) + (st >> 2);
  const int scol = (st & 3) * 8;
  // staging role: wave w stages panel p (0=A,1=B), rows rh..rh+63
  const int p = w >> 1, rh = (w & 1) * 64;
  const u16* gs = p ? Bw : Ab;
  const int gr = (p ? j0 : i0) + rh + srow;
  u16* dst0 = sh + p * 4096 + rh * 32;
  auto stage = [&](int bo, int k) {
    const int kn = k * 32;
#pragma unroll
    for (int rr = 0; rr < 64; rr += 16)
      gld16(&gs[(size_t)(gr + rr) * DD + kn + scol], dst0 + bo + rr * 32);
  };
  stage(0, 0);
  stage(8192, 1);
  bar_vm4();
  f32x4 acc[4][4] = {};
  int ro = 0;
  for (int kc = 0; kc < 16; ++kc) {
    if (kc <= 13) {
      int so = ro + 16384;
      if (so >= 24576) so -= 24576;
      stage(so, kc + 2);
    }
    const u16* As = sh + ro;
    const u16* Bs = sh + ro + 4096;
    short8 ar[4], br[4];
#pragma unroll
    for (int s = 0; s < 4; ++s) {
      ar[s] = *(const short8*)&As[(wi * 64 + s * 16) * 32 + roff];
      br[s] = *(const short8*)&Bs[(wj * 64 + s * 16) * 32 + roff];
    }
    __builtin_amdgcn_s_setprio(1);
#pragma unroll
    for (int si = 0; si < 4; ++si)
#pragma unroll
      for (int sj = 0; sj < 4; ++sj)
        acc[si][sj] = __builtin_amdgcn_mfma_f32_16x16x32_bf16(
            ar[si], br[sj], acc[si][sj], 0, 0, 0);
    __builtin_amdgcn_s_setprio(0);
    if (kc <= 13) bar_vm4();
    else if (kc == 14) bar_vm0();
    ro += 8192;
    if (ro == 24576) ro = 0;
  }
  const float al = ACT ? alpha_p[0] : 0.f;
#pragma unroll
  for (int si = 0; si < 4; ++si)
#pragma unroll
    for (int sj = 0; sj < 4; ++sj) {
      const int col = j0 + wj * 64 + sj * 16 + m16;
      const float bv = bias[col];
#pragma unroll
      for (int r = 0; r < 4; ++r) {
        const int row = i0 + wi * 64 + si * 16 + quad * 4 + r;
        float x = acc[si][sj][r] + bv;
        if (ACT) x = (x >= 0.f) ? x : al * x;
        ob[(size_t)row * DD + col] = f2bf(x);
      }
    }
}

// ---------------- row-wise L2 normalize: bf16 in -> bf16 out -----------------
__global__ __launch_bounds__(256) void rownorm_bf16(const u16* __restrict__ h,
                                                    u16* __restrict__ o) {
  const int row = blockIdx.x;
  const int t = threadIdx.x;
  const size_t base = (size_t)row * DD;
  float v0 = bf2f(h[base + t]);
  float v1 = bf2f(h[base + 256 + t]);
  float s = v0 * v0 + v1 * v1;
  s = wave_sum(s);
  __shared__ float wsum[4];
  const int lane = t & 63, wid = t >> 6;
  if (lane == 0) wsum[wid] = s;
  __syncthreads();
  if (t == 0) {
    float tot = wsum[0] + wsum[1] + wsum[2] + wsum[3];
    wsum[0] = 1.f / fmaxf(sqrtf(tot), 1e-12f);
  }
  __syncthreads();
  const float inv = wsum[0];
  o[base + t] = f2bf(v0 * inv);
  o[base + 256 + t] = f2bf(v1 * inv);
}

// ------------- fused similarity: depth-3 counted-vmcnt pipeline --------------
// tile 128(i) x 128(j), 512 thr (8 waves: ig = w&3 i-group, jh = w>>2 j-half).
// zb: [r11, r11m, r12, r12m, c12, c12m, c22, c22m] x NN.
// S22 symmetry: its row stats come from column sums (r22 == c22 etc).
// LDS (dynamic): 3 bufs x 4 panels x 8 KiB = 96 KiB -> 1 block/CU, 8 waves.
__global__ __launch_bounds__(512) void sim_mfma(
    const u16* __restrict__ na, const u16* __restrict__ nb,
    const int* __restrict__ mask, float* __restrict__ zb) {
  extern __shared__ __align__(16) u16 shm[];  // 3 * 4 * 4096 u16 = 96 KiB
  const int tid = threadIdx.x;
  const int w = tid >> 6, lane = tid & 63;
  const int quad = lane >> 4, m16 = lane & 15;
  const int ig = w & 3, jh = w >> 2;
  const int i0 = blockIdx.y * 128, j0 = blockIdx.x * 128;
  const int roff =
      (m16 >> 1) * 64 + (((((m16 & 1) << 2) | quad) ^ (m16 >> 1)) * 8);
  const int st = (lane & 7) ^ (lane >> 3);
  const int srow = 2 * (lane >> 3) + (st >> 2);
  const int scol = (st & 3) * 8;
  // staging role: wave w stages panel p, rows rh..rh+63 of that panel
  const int p = w >> 1, rh = (w & 1) * 64;
  const u16* gs = (p & 1) ? nb : na;  // panels: 0 na_i, 1 nb_i, 2 na_j, 3 nb_j
  const int gr = ((p < 2) ? i0 : j0) + rh + srow;
  u16* dst0 = shm + p * 4096 + rh * 32;
  auto stage = [&](int bo, int k) {
    const int kn = k * 32;
#pragma unroll
    for (int rr = 0; rr < 64; rr += 16)
      gld16(&gs[(size_t)(gr + rr) * DD + kn + scol], dst0 + bo + rr * 32);
  };
  stage(0, 0);
  stage(16384, 1);
  bar_vm4();
  f32x4 a11[2][4] = {}, a12[2][4] = {}, a22[2][4] = {};
  int ro = 0;
  for (int kc = 0; kc < 16; ++kc) {
    if (kc <= 13) {  // prefetch chunk kc+2 into buffer (kc+2)%3 (write-safe:
      int so = ro + 32768;  // its readers are behind the barrier just passed)
      if (so >= 49152) so -= 49152;
      stage(so, kc + 2);
    }
    const u16* Ai = shm + ro;
    const u16* Bi = shm + ro + 4096;
    const u16* Aj = shm + ro + 8192;
    const u16* Bj = shm + ro + 12288;
    short8 ai0 = *(const short8*)&Ai[(ig * 32) * 32 + roff];
    short8 ai1 = *(const short8*)&Ai[(ig * 32 + 16) * 32 + roff];
    short8 bi0 = *(const short8*)&Bi[(ig * 32) * 32 + roff];
    short8 bi1 = *(const short8*)&Bi[(ig * 32 + 16) * 32 + roff];
#pragma unroll
    for (int c = 0; c < 4; ++c) {
      short8 aj = *(const short8*)&Aj[(jh * 64 + c * 16) * 32 + roff];
      short8 bj = *(const short8*)&Bj[(jh * 64 + c * 16) * 32 + roff];
      __builtin_amdgcn_s_setprio(1);
      a11[0][c] = __builtin_amdgcn_mfma_f32_16x16x32_bf16(ai0, aj, a11[0][c], 0, 0, 0);
      a11[1][c] = __builtin_amdgcn_mfma_f32_16x16x32_bf16(ai1, aj, a11[1][c], 0, 0, 0);
      a12[0][c] = __builtin_amdgcn_mfma_f32_16x16x32_bf16(ai0, bj, a12[0][c], 0, 0, 0);
      a12[1][c] = __builtin_amdgcn_mfma_f32_16x16x32_bf16(ai1, bj, a12[1][c], 0, 0, 0);
      a22[0][c] = __builtin_amdgcn_mfma_f32_16x16x32_bf16(bi0, bj, a22[0][c], 0, 0, 0);
      a22[1][c] = __builtin_amdgcn_mfma_f32_16x16x32_bf16(bi1, bj, a22[1][c], 0, 0, 0);
      __builtin_amdgcn_s_setprio(0);
    }
    if (kc <= 13) bar_vm4();
    else if (kc == 14) bar_vm0();
    ro += 16384;
    if (ro == 49152) ro = 0;
  }
  // reductions overlay buffer 1 (free: kc=14 read buf2, kc=15 reads buf0;
  // buf1 last read at kc=13, two barriers ago; no gld16 outstanding)
  float* rred = (float*)(shm + 16384);  // [4][128] row stats
  float* cred = rred + 512;             // [4][128] col stats
  rred[tid] = 0.f;
  rred[tid + 512] = 0.f;
  __syncthreads();
  float rs11[2][4] = {}, rm11[2][4] = {}, rs12[2][4] = {}, rm12[2][4] = {};
  float cs12[4] = {}, cm12[4] = {}, cs22[4] = {}, cm22[4] = {};
#pragma unroll
  for (int t = 0; t < 2; ++t)
#pragma unroll
    for (int c = 0; c < 4; ++c) {
      const int gj = j0 + jh * 64 + c * 16 + m16;
#pragma unroll
      for (int r = 0; r < 4; ++r) {
        const int gi = i0 + ig * 32 + t * 16 + quad * 4 + r;
        const float mv = (float)mask[(size_t)gi * NN + gj];
        const float e11 = __expf(a11[t][c][r] * INV_TAU);
        const float e12 = __expf(a12[t][c][r] * INV_TAU);
        const float e22 = __expf(a22[t][c][r] * INV_TAU);
        rs11[t][r] += e11;
        rm11[t][r] += e11 * mv;
        rs12[t][r] += e12;
        rm12[t][r] += e12 * mv;
        cs12[c] += e12;
        cm12[c] += e12 * mv;
        cs22[c] += e22;
        cm22[c] += e22 * mv;
      }
    }
#pragma unroll
  for (int t = 0; t < 2; ++t)
#pragma unroll
    for (int r = 0; r < 4; ++r) {
      float v0 = rs11[t][r], v1 = rm11[t][r], v2 = rs12[t][r], v3 = rm12[t][r];
#pragma unroll
      for (int o = 1; o < 16; o <<= 1) {
        v0 += __shfl_xor(v0, o, 64);
        v1 += __shfl_xor(v1, o, 64);
        v2 += __shfl_xor(v2, o, 64);
        v3 += __shfl_xor(v3, o, 64);
      }
      if (m16 == 0) {
        const int il = ig * 32 + t * 16 + quad * 4 + r;
        atomicAdd(&rred[0 * 128 + il], v0);
        atomicAdd(&rred[1 * 128 + il], v1);
        atomicAdd(&rred[2 * 128 + il], v2);
        atomicAdd(&rred[3 * 128 + il], v3);
      }
    }
#pragma unroll
  for (int c = 0; c < 4; ++c) {
    float v0 = cs12[c], v1 = cm12[c], v2 = cs22[c], v3 = cm22[c];
    v0 += __shfl_xor(v0, 16, 64); v0 += __shfl_xor(v0, 32, 64);
    v1 += __shfl_xor(v1, 16, 64); v1 += __shfl_xor(v1, 32, 64);
    v2 += __shfl_xor(v2, 16, 64); v2 += __shfl_xor(v2, 32, 64);
    v3 += __shfl_xor(v3, 16, 64); v3 += __shfl_xor(v3, 32, 64);
    if (lane < 16) {
      const int jl = jh * 64 + c * 16 + lane;
      atomicAdd(&cred[0 * 128 + jl], v0);
      atomicAdd(&cred[1 * 128 + jl], v1);
      atomicAdd(&cred[2 * 128 + jl], v2);
      atomicAdd(&cred[3 * 128 + jl], v3);
    }
  }
  __syncthreads();
  if (tid < 128) {
#pragma unroll
    for (int q = 0; q < 4; ++q)
      atomicAdd(&zb[q * NN + i0 + tid], rred[q * 128 + tid]);
  } else if (tid < 256) {
    const int jl = tid - 128;
#pragma unroll
    for (int q = 0; q < 4; ++q)
      atomicAdd(&zb[(4 + q) * NN + j0 + jl], cred[q * 128 + jl]);
  }
}

// ---------------- local InfoNCE finalize -------------------------------------
__global__ __launch_bounds__(256) void local_fin(const float* __restrict__ zb,
                                                 float* __restrict__ scal) {
  const int i = blockIdx.x * 256 + threadIdx.x;
  const float r11 = zb[i], r11m = zb[NN + i];
  const float r12 = zb[2 * NN + i], r12m = zb[3 * NN + i];
  const float c12 = zb[4 * NN + i], c12m = zb[5 * NN + i];
  const float c22 = zb[6 * NN + i], c22m = zb[7 * NN + i];
  float l1 = -logf(r12m / (r11 + r12 - r11m));
  float l2 = -logf(c12m / (c22 + c12 - c22m));
  l1 = wave_sum(l1);
  l2 = wave_sum(l2);
  __shared__ float b1[4], b2[4];
  const int lane = threadIdx.x & 63, wid = threadIdx.x >> 6;
  if (lane == 0) { b1[wid] = l1; b2[wid] = l2; }
  __syncthreads();
  if (threadIdx.x == 0) {
    atomicAdd(&scal[0], b1[0] + b1[1] + b1[2] + b1[3]);
    atomicAdd(&scal[1], b2[0] + b2[1] + b2[2] + b2[3]);
  }
}

// ---------------- column means of z1, z2 (readouts) --------------------------
__global__ __launch_bounds__(256) void colmean(const float* __restrict__ z1,
                                               const float* __restrict__ z2,
                                               float* __restrict__ s1,
                                               float* __restrict__ s2) {
  const int c = blockIdx.x * 256 + threadIdx.x;
  const int r0 = blockIdx.y * 64;
  float a = 0.f, b = 0.f;
  for (int r = r0; r < r0 + 64; ++r) {
    a += z1[(size_t)r * DD + c];
    b += z2[(size_t)r * DD + c];
  }
  atomicAdd(&s1[c], a * (1.f / NN));
  atomicAdd(&s2[c], b * (1.f / NN));
}

// ---------------- paired D x D matvec, one wave per output row ---------------
__global__ __launch_bounds__(256) void matvec2(
    const float* __restrict__ M, const float* __restrict__ x1,
    const float* __restrict__ x2, const float* __restrict__ bias,
    const float* __restrict__ alpha_p, int act, float* __restrict__ y1,
    float* __restrict__ y2) {
  const float* x = blockIdx.y ? x2 : x1;
  float* y = blockIdx.y ? y2 : y1;
  const int row = (blockIdx.x * 256 + threadIdx.x) >> 6;
  const int lane = threadIdx.x & 63;
  float acc = 0.f;
#pragma unroll
  for (int t = 0; t < 8; ++t)
    acc = fmaf(M[(size_t)row * DD + lane + 64 * t], x[lane + 64 * t], acc);
  acc = wave_sum(acc);
  if (lane == 0) {
    if (bias) acc += bias[row];
    if (act) { const float al = alpha_p[0]; acc = (acc >= 0.f) ? acc : al * acc; }
    y[row] = acc;
  }
}

// ---------------- paired sigmoid/log reduce ----------------------------------
__global__ __launch_bounds__(256) void logsig2(
    const float* __restrict__ z1, const float* __restrict__ z2,
    const float* __restrict__ sm1, const float* __restrict__ sm2,
    float* __restrict__ scal) {
  const int ch = blockIdx.y;
  const float* z = ch ? z2 : z1;
  const float* sp = ch ? sm2 : sm1;
  const float* sn = ch ? sm1 : sm2;
  float* accP = ch ? &scal[4] : &scal[2];
  float* accN = ch ? &scal[3] : &scal[5];
  const int lane = threadIdx.x & 63;
  const int wid = threadIdx.x >> 6;
  const int row = blockIdx.x * 4 + wid;
  float dp = 0.f, dn = 0.f;
#pragma unroll
  for (int t = 0; t < 8; ++t) {
    const float zv = z[(size_t)row * DD + lane + 64 * t];
    dp = fmaf(zv, sp[lane + 64 * t], dp);
    dn = fmaf(zv, sn[lane + 64 * t], dn);
  }
  dp = wave_sum(dp);
  dn = wave_sum(dn);
  __shared__ float bp[4], bn[4];
  if (lane == 0) {
    const float sg = 1.f / (1.f + __expf(-dp));
    bp[wid] = -logf(sg + EPSV);
    const float sg2 = 1.f / (1.f + __expf(-dn));
    bn[wid] = -logf(1.f - sg2 + EPSV);
  }
  __syncthreads();
  if (threadIdx.x == 0) {
    atomicAdd(accP, bp[0] + bp[1] + bp[2] + bp[3]);
    atomicAdd(accN, bn[0] + bn[1] + bn[2] + bn[3]);
  }
}

// ---------------- final combine ----------------------------------------------
__global__ void combine(const float* __restrict__ scal, float* __restrict__ out) {
  const float local = 0.5f * (scal[0] + scal[1]) * (1.f / NN);
  const float glob = 0.25f * (scal[2] + scal[3] + scal[4] + scal[5]) * (1.f / NN);
  out[0] = 0.5f * local + 0.5f * glob;
}

extern "C" void kernel_launch(void* const* d_in, const int* in_sizes, int n_in,
                              void* d_out, int out_size, void* d_ws,
                              size_t ws_size, hipStream_t stream) {
  const float* z1 = (const float*)d_in[0];
  const float* z2 = (const float*)d_in[1];
  const float* lw1 = (const float*)d_in[2];
  const float* lb1 = (const float*)d_in[3];
  const float* la = (const float*)d_in[4];
  const float* lw2 = (const float*)d_in[5];
  const float* lb2 = (const float*)d_in[6];
  const float* gw1 = (const float*)d_in[7];
  const float* gb1 = (const float*)d_in[8];
  const float* ga = (const float*)d_in[9];
  const float* gw2 = (const float*)d_in[10];
  const float* gb2 = (const float*)d_in[11];
  const float* W = (const float*)d_in[12];
  const int* mask = (const int*)d_in[13];
  float* out = (float*)d_out;

  static bool attr_set = false;
  if (!attr_set) {
    (void)hipFuncSetAttribute(reinterpret_cast<const void*>(sim_mfma),
                              hipFuncAttributeMaxDynamicSharedMemorySize,
                              98304);
    attr_set = true;
  }

  const size_t ND = (size_t)NN * DD;
  u16* W1b = (u16*)d_ws;                 // [2][512*512] (W1b, W2b contiguous)
  u16* W2b = W1b + 512 * 512;
  u16* Ab = W1b + 2 * 512 * 512;         // [2][N*D] bf16
  u16* Bb = Ab + 2 * ND;                 // [2][N*D] bf16
  float* zbf = (float*)(Bb + 2 * ND);    // 8*NN
  float* s1 = zbf + 8 * NN;
  float* s2 = s1 + DD;
  float* scal = s2 + DD;                 // [sum1,sum2,P1,Ng1,P2,Ng2]
  float* t1 = scal + 16;
  float* hg1 = t1 + DD;
  float* summ1 = hg1 + DD;
  float* t2 = summ1 + DD;
  float* hg2 = t2 + DD;
  float* summ2 = hg2 + DD;

  hipMemsetAsync(zbf, 0, (8 * NN + 2 * DD + 16) * sizeof(float), stream);

  dim3 blk(256);
  // convert weights, then inputs: Ab = [bf16(z1); bf16(z2)]
  tobf16_2<<<512, blk, 0, stream>>>(lw1, lw2, W1b, 512 * 512 / 4);
  tobf16_2<<<4096, blk, 0, stream>>>(z1, z2, Ab, (int)(ND / 4));

  dim3 gg(4, 32, 2);  // 512/128, 4096/128, batch 2
  gemm_mfma<1><<<gg, blk, 0, stream>>>(Ab, W1b, lb1, la, Bb);     // prelu layer
  gemm_mfma<0><<<gg, blk, 0, stream>>>(Bb, W2b, lb2, la, Ab);     // second layer
  rownorm_bf16<<<2 * NN, blk, 0, stream>>>(Ab, Bb);               // -> na | nb

  sim_mfma<<<dim3(NN / 128, NN / 128), dim3(512), 98304, stream>>>(
      Bb, Bb + ND, mask, zbf);
  local_fin<<<NN / 256, blk, 0, stream>>>(zbf, scal);

  // global (DGI) part
  colmean<<<dim3(DD / 256, 64), blk, 0, stream>>>(z1, z2, s1, s2);
  matvec2<<<dim3(DD / 4, 2), blk, 0, stream>>>(gw1, s1, s2, gb1, ga, 1, t1, t2);
  matvec2<<<dim3(DD / 4, 2), blk, 0, stream>>>(gw2, t1, t2, gb2, nullptr, 0, hg1, hg2);
  matvec2<<<dim3(DD / 4, 2), blk, 0, stream>>>(W, hg1, hg2, nullptr, nullptr, 0, summ1, summ2);
  logsig2<<<dim3(NN / 4, 2), blk, 0, stream>>>(z1, z2, summ1, summ2, scal);

  combine<<<1, 1, 0, stream>>>(scal, out);
}